// Round 12
// baseline (245.421 us; speedup 1.0000x reference)
//
#include <hip/hip_runtime.h>
#include <hip/hip_bf16.h>

#define D_MODEL 96
#define D_INNER 192
#define BATCH 32
#define HH 56
#define WW 56
#define NPIX (BATCH*HH*WW)   // 100352
#define LN_EPS 1e-5f
#define TAPS 18432           // shorts per tap slab (96 oc * 192 ic)
#define TAPBYTES 36864

typedef unsigned short ushort_t;
typedef __attribute__((ext_vector_type(8))) short short8;   // 8 bf16 (4 VGPRs)
typedef __attribute__((ext_vector_type(4))) float f32x4;

// conv weights transposed to [tap][oc][ic] bf16 (331 KB) and
// in_proj live-half transposed to [oc=192][ic=96] bf16 (36.9 KB), module .data.
__device__ __align__(16) ushort_t g_Wt[9 * 96 * 192];
__device__ __align__(16) ushort_t g_Wit[192 * 96];

// round-to-nearest-even f32 -> bf16
static __device__ __forceinline__ unsigned short f2bf(float f) {
    unsigned u = __float_as_uint(f);
    unsigned r = (u + 0x7fffu + ((u >> 16) & 1u)) >> 16;
    return (unsigned short)r;
}

// ---------------------------------------------------------------------------
// Kernel 0: weight prep. (unchanged, verified)
// ---------------------------------------------------------------------------
__global__ __launch_bounds__(256) void k0_wt(const float* __restrict__ Wc,
                                             const float* __restrict__ Wi) {
    const int o = blockIdx.x * 256 + threadIdx.x;
    if (o < 9 * 96 * 192) {
        const int tap = o / (96 * 192);
        const int rem = o - tap * 96 * 192;
        const int oc = rem / 192;
        const int ic = rem - oc * 192;
        g_Wt[o] = f2bf(Wc[(tap * 192 + ic) * 96 + oc]);
    }
    if (o < 192 * 96) {
        const int oc = o / 96, ic = o - oc * 96;
        g_Wit[o] = f2bf(Wi[ic * 384 + oc]);
    }
}

// ---------------------------------------------------------------------------
// Kernel 1: LayerNorm + in_projection (96 -> live 192) via bf16 MFMA.
// (byte-identical to round 9/11, verified passing)
// ---------------------------------------------------------------------------
__global__ __launch_bounds__(256) void k1_ln_proj(
    const float* __restrict__ X, const float* __restrict__ ln_w,
    const float* __restrict__ ln_b, const float* __restrict__ b_in,
    ushort_t* __restrict__ X1)
{
    __shared__ ushort_t sH[64 * 104];    // 13,312 B (GEMM B-operand)
    __shared__ ushort_t sO[64 * 200];    // 25,600 B (output transpose)
    const int t = threadIdx.x;

    const int g = t >> 2, tig = t & 3;
    const int pix = blockIdx.x * 64 + g;
    const float* xp = X + (size_t)pix * 96 + tig * 24;
    float4 xq[6];
    float s = 0.f;
    #pragma unroll
    for (int c = 0; c < 6; ++c) {
        xq[c] = *(const float4*)(xp + c * 4);
        s += xq[c].x + xq[c].y + xq[c].z + xq[c].w;
    }
    s += __shfl_xor(s, 1, 4);
    s += __shfl_xor(s, 2, 4);
    const float mu = s * (1.f / 96.f);
    float v = 0.f;
    #pragma unroll
    for (int c = 0; c < 6; ++c) {
        const float d0 = xq[c].x - mu, d1 = xq[c].y - mu;
        const float d2 = xq[c].z - mu, d3 = xq[c].w - mu;
        v += d0 * d0 + d1 * d1 + d2 * d2 + d3 * d3;
    }
    v += __shfl_xor(v, 1, 4);
    v += __shfl_xor(v, 2, 4);
    const float rs = rsqrtf(v * (1.f / 96.f) + LN_EPS);
    #pragma unroll
    for (int c = 0; c < 6; ++c) {
        const float4 lw = *(const float4*)(ln_w + tig * 24 + c * 4);
        const float4 lb = *(const float4*)(ln_b + tig * 24 + c * 4);
        const unsigned p0 = (unsigned)f2bf((xq[c].x - mu) * rs * lw.x + lb.x)
                          | ((unsigned)f2bf((xq[c].y - mu) * rs * lw.y + lb.y) << 16);
        const unsigned p1 = (unsigned)f2bf((xq[c].z - mu) * rs * lw.z + lb.z)
                          | ((unsigned)f2bf((xq[c].w - mu) * rs * lw.w + lb.w) << 16);
        uint2 u; u.x = p0; u.y = p1;
        *(uint2*)&sH[g * 104 + tig * 24 + c * 4] = u;
    }
    __syncthreads();

    const int w = t >> 6, l = t & 63;
    const int lm = l & 15, lq = l >> 4;
    const ushort_t* hp = &sH[(w * 16 + lm) * 104 + lq * 8];

    f32x4 acc[12];
    const f32x4 zf = {0.f, 0.f, 0.f, 0.f};
    #pragma unroll
    for (int mt = 0; mt < 12; ++mt) acc[mt] = zf;

    #pragma unroll
    for (int kk = 0; kk < 3; ++kk) {
        const short8 hb = *(const short8*)(hp + kk * 32);
        #pragma unroll
        for (int mt = 0; mt < 12; ++mt) {
            const short8 wa = *(const short8*)(g_Wit + (mt * 16 + lm) * 96 + kk * 32 + lq * 8);
            acc[mt] = __builtin_amdgcn_mfma_f32_16x16x32_bf16(wa, hb, acc[mt], 0, 0, 0);
        }
    }

    #pragma unroll
    for (int mt = 0; mt < 12; ++mt) {
        const int oc0 = mt * 16 + lq * 4;
        const float4 bv = *(const float4*)(b_in + oc0);
        uint2 u;
        u.x = (unsigned)f2bf(acc[mt][0] + bv.x) | ((unsigned)f2bf(acc[mt][1] + bv.y) << 16);
        u.y = (unsigned)f2bf(acc[mt][2] + bv.z) | ((unsigned)f2bf(acc[mt][3] + bv.w) << 16);
        *(uint2*)&sO[(w * 16 + lm) * 200 + oc0] = u;
    }
    __syncthreads();

    const char* sOb = (const char*)sO + w * 16 * 400;
    char* gdst = (char*)X1 + (size_t)(blockIdx.x * 64 + w * 16) * 384;
    #pragma unroll
    for (int c = 0; c < 6; ++c) {
        const int gb = c * 1024 + l * 16;
        const int px = gb / 384, b = gb - px * 384;
        const uint4 val = *(const uint4*)(sOb + px * 400 + b);
        *(uint4*)(gdst + gb) = val;
    }
}

// ---------------------------------------------------------------------------
// Kernel 2: 3x3 conv (192 -> 96) MFMA + bias + SiLU + residual.
// ROUND-12 RESTRUCTURE: halo-in-LDS. Rounds 9-11 showed k2 bound by ~346 MB
// of 9x X1 halo re-reads missing L2 (FETCH 213 MB, all pipes <15%). Now the
// 10x10x192 bf16 halo is staged ONCE per block (40 KB, round-1-verified
// layout, zero-padded) -> main loop has ZERO global gathers. Weights: the
// round-9/10-verified single-buffer per-tap slab + reg-prefetch (36.9 KB,
// same XOR involution). LDS 76.9 KB -> 2 blocks/CU. Block = 384 thr =
// 6 waves; wave = all 64 px (4 m-tiles) x one 16-oc n-tile -> per tap:
// 6 B-ds_reads (amortized 4x) + 24 A-ds_reads + 24 MFMA. Grid 1568 =
// 8*196 XCD-swizzled. Epilogue: sY transpose + per-row coalesced float4.
// ---------------------------------------------------------------------------
__global__ __launch_bounds__(384, 3) void k2_conv_mfma(
    const ushort_t* __restrict__ X1, const float* __restrict__ conv_b,
    const float* __restrict__ X, float* __restrict__ OUT)
{
    __shared__ ushort_t sX[100 * 200];   // 40,000 B halo tile (px stride 400 B)
    __shared__ ushort_t sWs[TAPS];       // 36,864 B tap slab
    const int t = threadIdx.x;
    const int w = t >> 6, l = t & 63;
    const int lm = l & 15, lq = l >> 4;

    // bijective XCD swizzle: 1568 = 8 * 196; each XCD owns 4 images.
    const int lb = ((int)blockIdx.x & 7) * 196 + ((int)blockIdx.x >> 3);
    const int img = lb / 49, tile = lb - img * 49;
    const int ty = (tile / 7) * 8, tx = (tile % 7) * 8;
    const size_t imgbase = (size_t)img * 3136 * 192;

    // ---- stage halo 10x10x192 bf16 (zero-pad at image borders) ----
    for (int idx = t; idx < 2400; idx += 384) {      // 100 px * 24 uint4
        const int pix = idx / 24, q = idx - pix * 24;
        const int gr = ty + pix / 10 - 1, gc = tx + pix % 10 - 1;
        uint4 val = make_uint4(0u, 0u, 0u, 0u);
        if (gr >= 0 && gr < HH && gc >= 0 && gc < WW)
            val = *(const uint4*)(X1 + imgbase + (size_t)(gr * WW + gc) * 192 + q * 8);
        *(uint4*)&sX[pix * 200 + q * 8] = val;
    }

    // ---- stage tap-0 weight slab (linear src, swizzled LDS dest) ----
    const int sbase = t * 16;                        // 384 thr * 16 B * 6 = 36,864
    uint4 r[6];
    #pragma unroll
    for (int j = 0; j < 6; ++j)
        r[j] = *(const uint4*)((const char*)g_Wt + sbase + j * 6144);
    #pragma unroll
    for (int j = 0; j < 6; ++j) {
        const int D = sbase + j * 6144;
        *(uint4*)((char*)sWs + (D ^ (((D / 384) & 7) << 4))) = r[j];
    }
    __syncthreads();                                 // sX + sWs ready

    const int oc0 = w * 16;                          // wave's n-tile
    const int bkey = (lm & 7) << 4;
    const int brow = (oc0 + lm) * 384 + lq * 16;     // B-frag logical byte base

    f32x4 acc[4];
    const f32x4 zf = {0.f, 0.f, 0.f, 0.f};
    #pragma unroll
    for (int i = 0; i < 4; ++i) acc[i] = zf;

    #pragma unroll 1
    for (int tap = 0; tap < 9; ++tap) {
        // issue next tap's weight loads early (L2-resident, hidden under MFMA)
        if (tap < 8) {
            const char* gsrc = (const char*)g_Wt + (size_t)(tap + 1) * TAPBYTES;
            #pragma unroll
            for (int j = 0; j < 6; ++j)
                r[j] = *(const uint4*)(gsrc + sbase + j * 6144);
        }

        const int ky = tap / 3, kx = tap - (tap / 3) * 3;
        const ushort_t* ap[4];
        #pragma unroll
        for (int i = 0; i < 4; ++i) {
            const int p = i * 16 + lm;               // px within 8x8 tile
            const int pr = p >> 3, pc = p & 7;
            ap[i] = &sX[((pr + ky) * 10 + (pc + kx)) * 200 + lq * 8];
        }

        #pragma unroll
        for (int kk = 0; kk < 6; ++kk) {
            const int A = brow + kk * 64;
            const short8 b = *(const short8*)((const char*)sWs + (A ^ bkey));
            #pragma unroll
            for (int i = 0; i < 4; ++i) {
                const short8 a = *(const short8*)(ap[i] + kk * 32);
                acc[i] = __builtin_amdgcn_mfma_f32_16x16x32_bf16(a, b, acc[i], 0, 0, 0);
            }
        }

        if (tap < 8) {
            __syncthreads();                         // all waves done with sWs
            #pragma unroll
            for (int j = 0; j < 6; ++j) {
                const int D = sbase + j * 6144;
                *(uint4*)((char*)sWs + (D ^ (((D / 384) & 7) << 4))) = r[j];
            }
            __syncthreads();                         // slab ready
        }
    }

    // ---- epilogue: silu through LDS transpose, coalesced residual+store ----
    __syncthreads();                                 // all waves done with sX
    float* sY = (float*)sX;                          // 64 px * 100 dw = 25.6 KB
    const float bv = conv_b[oc0 + lm];
    #pragma unroll
    for (int i = 0; i < 4; ++i) {
        #pragma unroll
        for (int r4 = 0; r4 < 4; ++r4) {
            const float y = acc[i][r4] + bv;
            const float sig = 1.f / (1.f + __expf(-y));
            sY[(i * 16 + lq * 4 + r4) * 100 + oc0 + lm] = y * sig;
        }
    }
    __syncthreads();

    // 64 px * 96 ch = 6144 dwords; per tile-row (8 px) a 3 KB contiguous run
    #pragma unroll
    for (int c = 0; c < 4; ++c) {
        const int d = c * 1536 + t * 4;              // < 6144
        const int rrow = d / 768, dr = d - rrow * 768;
        const int px = rrow * 8 + dr / 96, b = dr - (dr / 96) * 96;
        const size_t gdw = ((size_t)img * 3136 + (ty + rrow) * 56 + tx) * 96 + dr;
        const f32x4 yv = *(const f32x4*)(sY + px * 100 + b);
        const float4 xv = *(const float4*)(X + gdw);
        float4 o;
        o.x = xv.x + yv[0]; o.y = xv.y + yv[1];
        o.z = xv.z + yv[2]; o.w = xv.w + yv[3];
        *(float4*)(OUT + gdw) = o;
    }
}

extern "C" void kernel_launch(void* const* d_in, const int* in_sizes, int n_in,
                              void* d_out, int out_size, void* d_ws, size_t ws_size,
                              hipStream_t stream) {
    (void)in_sizes; (void)n_in; (void)out_size; (void)ws_size;
    const float* X    = (const float*)d_in[0];
    const float* ln_w = (const float*)d_in[1];
    const float* ln_b = (const float*)d_in[2];
    const float* Wi   = (const float*)d_in[3];
    const float* b_in = (const float*)d_in[4];
    const float* Wc   = (const float*)d_in[5];
    const float* cb   = (const float*)d_in[6];
    float* OUT = (float*)d_out;
    ushort_t* X1 = (ushort_t*)d_ws;   // 100352*192 bf16 = 38.5 MB

    k0_wt<<<(9 * 96 * 192 + 255) / 256, 256, 0, stream>>>(Wc, Wi);
    k1_ln_proj<<<NPIX / 64, 256, 0, stream>>>(X, ln_w, ln_b, b_in, X1);
    k2_conv_mfma<<<NPIX / 64, 384, 0, stream>>>(X1, cb, X, OUT);
}